// Round 12
// baseline (55.339 us; speedup 1.0000x reference)
//
#include <hip/hip_runtime.h>

typedef __attribute__((ext_vector_type(8))) short short8;
typedef __attribute__((ext_vector_type(4))) float f32x4;

__device__ __forceinline__ unsigned short f2bf(float f) {
    union { float f; unsigned int u; } v; v.f = f;
    unsigned int u = v.u;
    unsigned int r = u + 0x7FFFu + ((u >> 16) & 1u);
    return (unsigned short)(r >> 16);
}

// Kernel A (R6/R8/R9-verified): W = proj_w @ v_w, bf16, PRE-SWIZZLED:
// W[e][c], e=(wn*64+ni*16+lrow), c=(kk*32+lkg*8+c8), lane=lkg*16+lrow
// -> idx = (((wn*8+kk)*4+ni)*64 + lane)*8 + c8.
__global__ __launch_bounds__(1024) void wmat_kernel(
    const float* __restrict__ v_w, const float* __restrict__ proj_w,
    unsigned short* __restrict__ Wm)
{
    __shared__ float red[4][256];
    const int e  = blockIdx.x;
    const int c  = threadIdx.x & 255;
    const int dq = threadIdx.x >> 8;   // 0..3

    const float* pw = proj_w + e * 256 + dq * 64;   // wave-uniform -> s_loads
    const float* vv = v_w + (dq * 64) * 256 + c;

    float acc = 0.f;
#pragma unroll 8
    for (int d = 0; d < 64; ++d)
        acc = fmaf(pw[d], vv[d * 256], acc);

    red[dq][c] = acc;
    __syncthreads();
    if (threadIdx.x < 256) {
        float s = red[0][c] + red[1][c] + red[2][c] + red[3][c];
        const int wn = e >> 6, ni = (e >> 4) & 3, lrow = e & 15;
        const int kk = c >> 5, lkg = (c >> 3) & 3, c8 = c & 7;
        const int lane = lkg * 16 + lrow;
        const int idxo = ((((wn * 8 + kk) * 4 + ni) * 64 + lane) * 8) + c8;
        Wm[idxo] = f2bf(s);
    }
}

// Kernel B: one block per 8x8-PIXEL 2D TILE (M=64 rows of 256 ch).
// 512 blocks x 512 threads, LDS 32KB (ybuf only) -> 2 blocks/CU avg.
// 2D tile cuts x halo amplification 3.19x -> 1.56x (unique 107->57MB).
// GEMM: BARRIER-FREE; A via conflict-free swizzled ds_read_b128, B direct
// from pre-swizzled global Wm (1KB/wave-load, 67MB total = half of R9).
// Epilogue: R9 full-line transpose in two 32-row rounds (tile reuses ybuf).
__global__ __launch_bounds__(512, 8) void fused_kernel(
    const float* __restrict__ x, const unsigned short* __restrict__ Wm,
    const float* __restrict__ proj_b, float* __restrict__ out)
{
    const int idx = ((blockIdx.x & 7) << 6) | (blockIdx.x >> 3);  // 512=8*64 bijective; image per XCD
    const int b   = idx >> 6;                // 0..7
    const int h0  = ((idx >> 3) & 7) * 8;    // row band
    const int wc0 = (idx & 7) * 8;           // col band
    const int t   = threadIdx.x;

    __shared__ alignas(16) char lds[32768];  // ybuf bf16 [64px][256ch] | f32 tile reuse

    const float A1  = (float)(1.0 / 10.71828182845904523536);                 // 1/(e+8)
    const float A0D = (float)(2.71828182845904523536 / 10.71828182845904523536) - A1; // A0-A1

    // ---- blur: 16 strips (8 rows x 2 col-quads, 4px each) x 32 ch-chunks ----
    {
        const int strip = t >> 5;        // 0..15
        const int rr    = strip >> 1;    // 0..7 local row
        const int q     = strip & 1;     // 0..1 col quad
        const int c0    = (t & 31) * 8;  // 8-channel chunk
        const int gh    = h0 + rr;       // global output row
        const int gw0   = wc0 + q * 4;   // first output col of strip

        const f32x4 z = {0.f, 0.f, 0.f, 0.f};
        f32x4 acc[4][2];
#pragma unroll
        for (int i = 0; i < 4; ++i) { acc[i][0] = z; acc[i][1] = z; }

        for (int gr = gh - 1; gr <= gh + 1; ++gr) {
            if (gr < 0 || gr >= 64) continue;
            const bool top = (gr == gh - 1);
            const float* xr = x + (((size_t)b * 64 + gr) * 64) * 256 + c0;

            f32x4 pm0, pm1, pc0, pc1;
            if (gw0 == 0) { pm0 = z; pm1 = z; }
            else {
                pm0 = *(const f32x4*)(xr + (gw0 - 1) * 256);
                pm1 = *(const f32x4*)(xr + (gw0 - 1) * 256 + 4);
            }
            pc0 = *(const f32x4*)(xr + gw0 * 256);
            pc1 = *(const f32x4*)(xr + gw0 * 256 + 4);

#pragma unroll
            for (int i = 0; i < 4; ++i) {
                const int gwn = gw0 + i + 1;
                f32x4 pn0 = z, pn1 = z;
                if (gwn < 64) {
                    pn0 = *(const f32x4*)(xr + gwn * 256);
                    pn1 = *(const f32x4*)(xr + gwn * 256 + 4);
                }
                acc[i][0] += A1 * (pm0 + pc0 + pn0);
                acc[i][1] += A1 * (pm1 + pc1 + pn1);
                if (top) {   // tap k=0 extra weight on x[h-1][w-1]
                    acc[i][0] += A0D * pm0;
                    acc[i][1] += A0D * pm1;
                }
                pm0 = pc0; pm1 = pc1; pc0 = pn0; pc1 = pn1;
            }
        }

        // pack to bf16, ybuf row p = rr*8 + q*4 + i, swizzle byte ^= (p&7)<<4
#pragma unroll
        for (int i = 0; i < 4; ++i) {
            const int p = rr * 8 + q * 4 + i;    // local px in [0,64)
            union { short8 v; unsigned short u[8]; } pk;
#pragma unroll
            for (int j = 0; j < 4; ++j) {
                pk.u[j]     = f2bf(acc[i][0][j]);
                pk.u[4 + j] = f2bf(acc[i][1][j]);
            }
            unsigned baddr = ((unsigned)p * 512u + (unsigned)c0 * 2u) ^ (((unsigned)(p & 7)) << 4);
            *reinterpret_cast<short8*>(lds + baddr) = pk.v;
        }
    }
    __syncthreads();   // ybuf ready

    // ---- GEMM (barrier-free): 8 waves = 2(wm) x 4(wn); 32px x 64e per wave ----
    const int w    = t >> 6;          // 0..7
    const int lane = t & 63;
    const int wm   = w >> 2;          // 0..1 -> px rows [wm*32, +32)
    const int wn   = w & 3;           // 0..3 -> e quarter
    const int lrow = lane & 15;
    const int lkg  = lane >> 4;       // 0..3

    f32x4 acc2[2][4];
    {
        const f32x4 z = {0.f, 0.f, 0.f, 0.f};
#pragma unroll
        for (int mi = 0; mi < 2; ++mi)
#pragma unroll
            for (int ni = 0; ni < 4; ++ni) acc2[mi][ni] = z;
    }

    const unsigned short* wb = Wm + (wn << 14) + (lane << 3); // pre-swizzled base

#pragma unroll
    for (int kk = 0; kk < 8; ++kk) {
        short8 a[2];
#pragma unroll
        for (int mi = 0; mi < 2; ++mi) {
            const int row = wm * 32 + mi * 16 + lrow;
            unsigned abyte = ((unsigned)row * 512u + (unsigned)(kk * 64 + lkg * 16))
                             ^ (((unsigned)(row & 7)) << 4);
            a[mi] = *reinterpret_cast<const short8*>(lds + abyte);
        }
#pragma unroll
        for (int ni = 0; ni < 4; ++ni) {
            short8 bf = *reinterpret_cast<const short8*>(wb + (kk << 11) + (ni << 9));
#pragma unroll
            for (int mi = 0; mi < 2; ++mi)
                acc2[mi][ni] = __builtin_amdgcn_mfma_f32_16x16x32_bf16(bf, a[mi], acc2[mi][ni], 0, 0, 0);
        }
    }
    __syncthreads();   // ybuf reads done; lds becomes f32 tile [32][256]

    // ---- epilogue: two 32-row rounds of LDS transpose + full-line stores ----
    // D layout (verified): lane holds e = wn*64+ni*16+lkg*4+(0..3) for px row.
    const f32x4 bias = *reinterpret_cast<const f32x4*>(proj_b + lane * 4);

#pragma unroll
    for (int half = 0; half < 2; ++half) {
        if (wm == half) {
#pragma unroll
            for (int mi = 0; mi < 2; ++mi) {
#pragma unroll
                for (int ni = 0; ni < 4; ++ni) {
                    const int trow = mi * 16 + lrow;   // tile row 0..31
                    const unsigned e0 = (unsigned)(wn * 64 + ni * 16 + lkg * 4);
                    unsigned baddr = ((unsigned)trow * 1024u + e0 * 4u)
                                     ^ (((unsigned)(trow & 7)) << 4);
                    *reinterpret_cast<f32x4*>(lds + baddr) = acc2[mi][ni];
                }
            }
        }
        __syncthreads();

        // all 8 waves store 32 rows: tile row r -> local px p = half*32 + r
#pragma unroll
        for (int j = 0; j < 4; ++j) {
            const int r = j * 8 + w;                  // 0..31
            const int p = half * 32 + r;              // local px
            const int gh = h0 + (p >> 3);
            const int gw = wc0 + (p & 7);
            unsigned baddr = ((unsigned)r * 1024u + (unsigned)lane * 16u)
                             ^ (((unsigned)(r & 7)) << 4);
            f32x4 v = *reinterpret_cast<const f32x4*>(lds + baddr) + bias;
            __builtin_nontemporal_store(
                v, reinterpret_cast<f32x4*>(out + (((size_t)b * 64 + gh) * 64 + gw) * 256 + lane * 4));
        }
        __syncthreads();
    }
}

extern "C" void kernel_launch(void* const* d_in, const int* in_sizes, int n_in,
                              void* d_out, int out_size, void* d_ws, size_t ws_size,
                              hipStream_t stream) {
    const float* x      = (const float*)d_in[0];
    const float* v_w    = (const float*)d_in[1];
    const float* proj_w = (const float*)d_in[2];
    const float* proj_b = (const float*)d_in[3];
    float* out = (float*)d_out;
    unsigned short* Wm = (unsigned short*)d_ws;   // 65536 bf16 = 128 KB, swizzled

    wmat_kernel<<<256, 1024, 0, stream>>>(v_w, proj_w, Wm);
    fused_kernel<<<512, 512, 0, stream>>>(x, Wm, proj_b, out);
}

// Round 13
// 28.042 us; speedup vs baseline: 1.9734x; 1.9734x over previous
//
#include <hip/hip_runtime.h>

typedef __attribute__((ext_vector_type(8))) short short8;
typedef __attribute__((ext_vector_type(4))) float f32x4;

__device__ __forceinline__ unsigned short f2bf(float f) {
    union { float f; unsigned int u; } v; v.f = f;
    unsigned int u = v.u;
    unsigned int r = u + 0x7FFFu + ((u >> 16) & 1u);
    return (unsigned short)(r >> 16);
}

// Kernel A (R6/R8/R9-verified): W = proj_w @ v_w, bf16, PRE-SWIZZLED:
// W[e][c], e=(wn*64+ni*16+lrow), c=(kk*32+lkg*8+c8), lane=lkg*16+lrow
// -> idx = (((wn*8+kk)*4+ni)*64 + lane)*8 + c8.
__global__ __launch_bounds__(1024) void wmat_kernel(
    const float* __restrict__ v_w, const float* __restrict__ proj_w,
    unsigned short* __restrict__ Wm)
{
    __shared__ float red[4][256];
    const int e  = blockIdx.x;
    const int c  = threadIdx.x & 255;
    const int dq = threadIdx.x >> 8;   // 0..3

    const float* pw = proj_w + e * 256 + dq * 64;   // wave-uniform -> s_loads
    const float* vv = v_w + (dq * 64) * 256 + c;

    float acc = 0.f;
#pragma unroll 8
    for (int d = 0; d < 64; ++d)
        acc = fmaf(pw[d], vv[d * 256], acc);

    red[dq][c] = acc;
    __syncthreads();
    if (threadIdx.x < 256) {
        float s = red[0][c] + red[1][c] + red[2][c] + red[3][c];
        const int wn = e >> 6, ni = (e >> 4) & 3, lrow = e & 15;
        const int kk = c >> 5, lkg = (c >> 3) & 3, c8 = c & 7;
        const int lane = lkg * 16 + lrow;
        const int idxo = ((((wn * 8 + kk) * 4 + ni) * 64 + lane) * 8) + c8;
        Wm[idxo] = f2bf(s);
    }
}

// Kernel B: R9 structure VERBATIM except __launch_bounds__(512,6).
// R10/R12 profiles showed VGPR_Count=32: the old (512,8) bound capped the
// unified VGPR+AGPR file at 64/lane -> blur spilled to scratch (warm FETCH
// 80MB, WRITE 94MB for a 33.5MB output = ~60MB spill traffic). (512,6)
// gives ~80 regs/lane: no spill, 3 blocks/CU = 24 waves/CU.
__global__ __launch_bounds__(512, 6) void fused_kernel(
    const float* __restrict__ x, const unsigned short* __restrict__ Wm,
    const float* __restrict__ proj_b, float* __restrict__ out)
{
    const int idx   = ((blockIdx.x & 7) << 7) | (blockIdx.x >> 3);  // 1024=8*128, bijective
    const int b     = idx >> 7;
    const int h     = (idx >> 1) & 63;
    const int wbase = (idx & 1) * 32;
    const int t     = threadIdx.x;

    __shared__ alignas(16) char lds[32768];   // [0,16K) ybuf bf16 | [16K,32K) wbuf | f32 tile reuse

    const float A1  = (float)(1.0 / 10.71828182845904523536);                 // 1/(e+8)
    const float A0D = (float)(2.71828182845904523536 / 10.71828182845904523536) - A1; // A0-A1

    // ---------------- blur: 16 strips(2px) x 32 chunks(8ch) = 512 ----------------
    {
        const int strip = t >> 5;         // 0..15
        const int c0    = (t & 31) * 8;   // 8-channel chunk
        const int px0   = strip * 2;      // local pixel in [0,32)
        const int gw0   = wbase + px0;    // global pixel column

        const f32x4 z = {0.f, 0.f, 0.f, 0.f};
        f32x4 acc[2][2];
#pragma unroll
        for (int i = 0; i < 2; ++i) { acc[i][0] = z; acc[i][1] = z; }

        for (int r = h - 1; r <= h + 1; ++r) {
            if (r < 0 || r >= 64) continue;
            const bool top = (r == h - 1);
            const float* xr = x + (((size_t)b * 64 + r) * 64) * 256 + c0;

            f32x4 pm0, pm1, pc0, pc1;
            if (gw0 == 0) { pm0 = z; pm1 = z; }
            else {
                pm0 = *(const f32x4*)(xr + (gw0 - 1) * 256);
                pm1 = *(const f32x4*)(xr + (gw0 - 1) * 256 + 4);
            }
            pc0 = *(const f32x4*)(xr + gw0 * 256);
            pc1 = *(const f32x4*)(xr + gw0 * 256 + 4);

#pragma unroll
            for (int i = 0; i < 2; ++i) {
                const int gwn = gw0 + i + 1;
                f32x4 pn0 = z, pn1 = z;
                if (gwn < 64) {
                    pn0 = *(const f32x4*)(xr + gwn * 256);
                    pn1 = *(const f32x4*)(xr + gwn * 256 + 4);
                }
                acc[i][0] += A1 * (pm0 + pc0 + pn0);
                acc[i][1] += A1 * (pm1 + pc1 + pn1);
                if (top) {   // tap k=0 extra weight on x[h-1][w-1]
                    acc[i][0] += A0D * pm0;
                    acc[i][1] += A0D * pm1;
                }
                pm0 = pc0; pm1 = pc1; pc0 = pn0; pc1 = pn1;
            }
        }

        // pack to bf16, write swizzled: byte ^= ((w&7)<<4)
#pragma unroll
        for (int i = 0; i < 2; ++i) {
            const int w = px0 + i;        // local row in [0,32)
            union { short8 v; unsigned short u[8]; } pk;
#pragma unroll
            for (int j = 0; j < 4; ++j) {
                pk.u[j]     = f2bf(acc[i][0][j]);
                pk.u[4 + j] = f2bf(acc[i][1][j]);
            }
            unsigned baddr = ((unsigned)w * 512u + (unsigned)c0 * 2u) ^ (((unsigned)(w & 7)) << 4);
            *reinterpret_cast<short8*>(lds + baddr) = pk.v;
        }
    }

    // ---------------- GEMM: 8 waves = 2(mi) x 4(wn), W staged in LDS ----------------
    const int w    = t >> 6;          // wave 0..7
    const int lane = t & 63;
    const int mi   = w >> 2;          // 0..1  -> 16-px half
    const int wn   = w & 3;           // 0..3  -> 64-e quarter
    const int lrow = lane & 15;
    const int lkg  = lane >> 4;       // 0..3
    const int row  = mi * 16 + lrow;  // local pixel this lane produces

    f32x4 acc2[4];
    {
        const f32x4 z = {0.f, 0.f, 0.f, 0.f};
#pragma unroll
        for (int ni = 0; ni < 4; ++ni) acc2[ni] = z;
    }

    const unsigned abase = (unsigned)row * 512u;
    const unsigned aswz  = ((unsigned)(row & 7)) << 4;

    for (int kk = 0; kk < 8; ++kk) {
        __syncthreads();   // kk=0: blur done; kk>0: prev chunk's B-reads done
        // stage W chunk kk: wave w copies groups g = 2w, 2w+1 (1KB each, coalesced)
#pragma unroll
        for (int q = 0; q < 2; ++q) {
            const int g = w * 2 + q;                       // g = wn_s*4 + ni_s
            const unsigned short* src =
                Wm + ((((size_t)(g >> 2) * 8 + kk) * 4 + (g & 3)) * 64 + lane) * 8;
            __builtin_amdgcn_global_load_lds(src, (lds + 16384 + g * 1024), 16, 0, 0);
        }
        __syncthreads();   // staging complete (vmcnt drained before barrier)

        const unsigned abyte = (abase + (unsigned)(kk * 64 + lkg * 16)) ^ aswz;
        short8 a = *reinterpret_cast<const short8*>(lds + abyte);
#pragma unroll
        for (int ni = 0; ni < 4; ++ni) {
            short8 bf = *reinterpret_cast<const short8*>(
                lds + 16384 + ((wn * 4 + ni) * 64 + lane) * 16);
            acc2[ni] = __builtin_amdgcn_mfma_f32_16x16x32_bf16(bf, a, acc2[ni], 0, 0, 0);
        }
    }
    __syncthreads();   // all B/A reads done; lds becomes f32 out-tile [32][256]

    // ---------------- epilogue: transpose via f32 LDS, full-line stores ---------
    // D layout (R3/R6/R8-verified): lane holds e = wn*64+ni*16+lkg*4+(0..3), px=row.
#pragma unroll
    for (int ni = 0; ni < 4; ++ni) {
        const unsigned e0 = (unsigned)(wn * 64 + ni * 16 + lkg * 4);
        unsigned baddr = ((unsigned)row * 1024u + e0 * 4u) ^ (((unsigned)(row & 7)) << 4);
        *reinterpret_cast<f32x4*>(lds + baddr) = acc2[ni];
    }
    __syncthreads();

    const f32x4 bias = *reinterpret_cast<const f32x4*>(proj_b + lane * 4);
    const size_t pxbase = (size_t)idx * 32;
#pragma unroll
    for (int j = 0; j < 4; ++j) {
        const int r = j * 8 + w;    // 8 waves x 4 rows = 32 rows
        unsigned baddr = ((unsigned)r * 1024u + (unsigned)lane * 16u)
                         ^ (((unsigned)(r & 7)) << 4);
        f32x4 v = *reinterpret_cast<const f32x4*>(lds + baddr) + bias;
        __builtin_nontemporal_store(v, reinterpret_cast<f32x4*>(out + (pxbase + r) * 256 + lane * 4));
    }
}

extern "C" void kernel_launch(void* const* d_in, const int* in_sizes, int n_in,
                              void* d_out, int out_size, void* d_ws, size_t ws_size,
                              hipStream_t stream) {
    const float* x      = (const float*)d_in[0];
    const float* v_w    = (const float*)d_in[1];
    const float* proj_w = (const float*)d_in[2];
    const float* proj_b = (const float*)d_in[3];
    float* out = (float*)d_out;
    unsigned short* Wm = (unsigned short*)d_ws;   // 65536 bf16 = 128 KB, swizzled

    wmat_kernel<<<256, 1024, 0, stream>>>(v_w, proj_w, Wm);
    fused_kernel<<<1024, 512, 0, stream>>>(x, Wm, proj_b, out);
}